// Round 5
// baseline (85.244 us; speedup 1.0000x reference)
//
#include <hip/hip_runtime.h>

#define Bc 2
#define Hc 32
#define N1c 1024
#define Nc 1023
#define BLOCK 256
#define PLANE (N1c * N1c)

typedef __attribute__((ext_vector_type(8))) short bf16x8;
typedef __attribute__((ext_vector_type(4))) float f32x4;

// compiler-visible RNE f32->bf16 (no inline asm: MFMA operand hazards stay
// under the compiler's hazard recognizer)
__device__ __forceinline__ unsigned short f2bf(float a) {
    unsigned ua = __float_as_uint(a);
    ua = (ua + 0x7fffu + ((ua >> 16) & 1u)) >> 16;
    return (unsigned short)ua;
}

__global__ __launch_bounds__(BLOCK) void se3_head_kernel(
    const float* __restrict__ x,    // [B,N,3]
    const float* __restrict__ qk,   // [B,H,N1,N1]
    const float* __restrict__ W1,   // [H,H]
    const float* __restrict__ b1,   // [H]
    const float* __restrict__ W2,   // [1,H]
    const float* __restrict__ b2,   // [1]
    float* __restrict__ out)        // [B,N,3]
{
    __shared__ float xs[N1c][3];    // x broadcast table (row 1023 zeroed)
    __shared__ float red[4][4];

    const int bi   = blockIdx.x;
    const int b    = bi / Nc;
    const int i    = bi % Nc;
    const int t    = threadIdx.x;
    const int w    = t >> 6;
    const int lane = t & 63;
    const int jl   = lane & 15;   // B-col (j) and A-row (g) lane index
    const int lk   = lane >> 4;   // k-chunk

    const float* qk_b = qk + (size_t)b * Hc * PLANE + (size_t)(i + 1) * N1c;
    const float* xb   = x + (size_t)b * Nc * 3;

    // ---- stage x once ----
    for (int rr = t; rr < N1c; rr += BLOCK) {
        float v0 = 0.f, v1 = 0.f, v2 = 0.f;
        if (rr < Nc) { v0 = xb[rr*3]; v1 = xb[rr*3+1]; v2 = xb[rr*3+2]; }
        xs[rr][0] = v0; xs[rr][1] = v1; xs[rr][2] = v2;
    }

    // ---- per-lane constants (plain W1 as A; b1 as C-operand; w2 applied
    //      post-relu — all pieces verified in R2/R3) ----
    bf16x8 A0, A1;   // A[row=g=jl][k=lk*8+e], rows g and g+16
    #pragma unroll
    for (int e = 0; e < 8; ++e) {
        ((unsigned short*)&A0)[e] = f2bf(W1[jl * Hc + lk*8 + e]);
        ((unsigned short*)&A1)[e] = f2bf(W1[(jl + 16) * Hc + lk*8 + e]);
    }
    f32x4 cb0, cb1, w2v0, w2v1;   // indexed by C-row g = lk*4 + r (and +16)
    #pragma unroll
    for (int r = 0; r < 4; ++r) {
        const int g0 = lk*4 + r, g1 = 16 + lk*4 + r;
        cb0[r]  = b1[g0];
        cb1[r]  = b1[g1];
        w2v0[r] = W2[g0];
        w2v1[r] = W2[g1];
    }
    const float b2v = b2[0];

    __syncthreads();   // xs visible; no barriers in the main loop

    const unsigned vb = (unsigned)(lk * 8) * (unsigned)PLANE;
    float S = 0.f, T0 = 0.f, T1 = 0.f, T2 = 0.f;

    // B-fragment straight from global: lane holds q[h=lk*8+e][w*256+m*16+jl]
    auto LOADQ = [&](float (&f)[8], int m) {
        const int jglob = w * 256 + m * 16 + jl;
        const int jc    = jglob < Nc ? jglob : Nc - 1;   // clamp; masked below
        const unsigned idx = vb + (unsigned)(jc + 1);
        #pragma unroll
        for (int e = 0; e < 8; ++e)
            f[e] = qk_b[idx + (unsigned)e * (unsigned)PLANE];
    };

    auto COMP = [&](const float (&f)[8], int m) {
        bf16x8 Bq;
        #pragma unroll
        for (int e = 0; e < 8; ++e)
            ((unsigned short*)&Bq)[e] = f2bf(f[e]);
        f32x4 c0 = __builtin_amdgcn_mfma_f32_16x16x32_bf16(A0, Bq, cb0, 0, 0, 0);
        f32x4 c1 = __builtin_amdgcn_mfma_f32_16x16x32_bf16(A1, Bq, cb1, 0, 0, 0);
        float s = 0.f;
        #pragma unroll
        for (int r = 0; r < 4; ++r) {
            s = fmaf(fmaxf(c0[r], 0.f), w2v0[r], s);
            s = fmaf(fmaxf(c1[r], 0.f), w2v1[r], s);
        }
        s += __shfl_xor(s, 16);   // sum over the 4 lk groups -> full sum over g
        s += __shfl_xor(s, 32);
        const int jglob = w * 256 + m * 16 + jl;
        const float cp = (jglob < Nc) ? (s + b2v) : 0.f;  // 4 copies per j; /4 later
        S += cp;
        T0 = fmaf(xs[jglob][0], cp, T0);   // xs[1023]=0 and cp=0 there
        T1 = fmaf(xs[jglob][1], cp, T1);
        T2 = fmaf(xs[jglob][2], cp, T2);
    };

    // 4-deep software pipeline: 32 outstanding dword loads per thread
    float f0[8], f1[8], f2[8], f3[8];
    LOADQ(f0, 0); LOADQ(f1, 1); LOADQ(f2, 2); LOADQ(f3, 3);
    #pragma unroll
    for (int m = 0; m < 16; m += 4) {
        COMP(f0, m);     if (m + 4 < 16) LOADQ(f0, m + 4);
        COMP(f1, m + 1); if (m + 5 < 16) LOADQ(f1, m + 5);
        COMP(f2, m + 2); if (m + 6 < 16) LOADQ(f2, m + 6);
        COMP(f3, m + 3); if (m + 7 < 16) LOADQ(f3, m + 7);
    }

    // ---- block reduction ----
    #pragma unroll
    for (int off = 32; off > 0; off >>= 1) {
        S  += __shfl_down(S,  off);
        T0 += __shfl_down(T0, off);
        T1 += __shfl_down(T1, off);
        T2 += __shfl_down(T2, off);
    }
    if (lane == 0) { red[w][0] = S; red[w][1] = T0; red[w][2] = T1; red[w][3] = T2; }
    __syncthreads();

    if (t == 0) {
        float s = 0.f, u0 = 0.f, u1 = 0.f, u2 = 0.f;
        #pragma unroll
        for (int q = 0; q < 4; ++q) {
            s += red[q][0]; u0 += red[q][1]; u1 += red[q][2]; u2 += red[q][3];
        }
        s *= 0.25f; u0 *= 0.25f; u1 *= 0.25f; u2 *= 0.25f;  // lk 4x duplication
        const float xi0 = xs[i][0], xi1 = xs[i][1], xi2 = xs[i][2];
        out[(b*Nc + i)*3 + 0] = fmaf(xi0, s, xi0) - u0;
        out[(b*Nc + i)*3 + 1] = fmaf(xi1, s, xi1) - u1;
        out[(b*Nc + i)*3 + 2] = fmaf(xi2, s, xi2) - u2;
    }
}

extern "C" void kernel_launch(void* const* d_in, const int* in_sizes, int n_in,
                              void* d_out, int out_size, void* d_ws, size_t ws_size,
                              hipStream_t stream) {
    const float* x  = (const float*)d_in[0];
    const float* qk = (const float*)d_in[1];
    const float* W1 = (const float*)d_in[2];
    const float* b1 = (const float*)d_in[3];
    const float* W2 = (const float*)d_in[4];
    const float* b2 = (const float*)d_in[5];
    float* out = (float*)d_out;

    se3_head_kernel<<<dim3(Bc * Nc), dim3(BLOCK), 0, stream>>>(
        x, qk, W1, b1, W2, b2, out);
}

// Round 6
// 75.531 us; speedup vs baseline: 1.1286x; 1.1286x over previous
//
#include <hip/hip_runtime.h>
#include <hip/hip_bf16.h>

#define Bc 2
#define Hc 32
#define N1c 1024
#define Nc 1023
#define BLOCK 256
#define PLANE (N1c * N1c)
#define LDSW 40   // ushorts per LDS row (80 B); 16B-aligned, R2/R3-verified

typedef __attribute__((ext_vector_type(8))) short bf16x8;
typedef __attribute__((ext_vector_type(4))) float f32x4;

// compiler-visible RNE f32->bf16 (host-constant prep only)
__device__ __forceinline__ unsigned short f2bf(float a) {
    unsigned ua = __float_as_uint(a);
    ua = (ua + 0x7fffu + ((ua >> 16) & 1u)) >> 16;
    return (unsigned short)ua;
}

__global__ __launch_bounds__(BLOCK) void se3_head_kernel(
    const float* __restrict__ x,    // [B,N,3]
    const float* __restrict__ qk,   // [B,H,N1,N1]
    const float* __restrict__ W1,   // [H,H]
    const float* __restrict__ b1,   // [H]
    const float* __restrict__ W2,   // [1,H]
    const float* __restrict__ b2,   // [1]
    float* __restrict__ out)        // [B,N,3]
{
    __shared__ unsigned short qs[4][64][LDSW];  // wave-private strip (reused per tile)
    __shared__ float xs[N1c][3];                // x broadcast table (row 1023 zeroed)
    __shared__ float red[4][4];

    const int bi   = blockIdx.x;
    const int b    = bi / Nc;
    const int i    = bi % Nc;
    const int t    = threadIdx.x;
    const int w    = t >> 6;
    const int lane = t & 63;
    const int lrow = lane & 15;   // A-row (j within 16) / B-col (g) / C-col (g)
    const int lk   = lane >> 4;   // k-chunk / C-row-quad

    const float* qk_b = qk + (size_t)b * Hc * PLANE + (size_t)(i + 1) * N1c;
    const float* xb   = x + (size_t)b * Nc * 3;

    // ---- stage x once (row 1023 zeroed) ----
    for (int rr = t; rr < N1c; rr += BLOCK) {
        float v0 = 0.f, v1 = 0.f, v2 = 0.f;
        if (rr < Nc) { v0 = xb[rr*3]; v1 = xb[rr*3+1]; v2 = xb[rr*3+2]; }
        xs[rr][0] = v0; xs[rr][1] = v1; xs[rr][2] = v2;
    }

    // ---- per-lane constants (R5-verified numerics, R2-verified geometry) ----
    bf16x8 B0, B1;   // W1^T fragments: B[k=lk*8+e][n=g=lrow], rows g and g+16
    #pragma unroll
    for (int e = 0; e < 8; ++e) {
        ((unsigned short*)&B0)[e] = f2bf(W1[lrow * Hc + lk*8 + e]);
        ((unsigned short*)&B1)[e] = f2bf(W1[(lrow + 16) * Hc + lk*8 + e]);
    }
    const float w2a = W2[lrow], w2b = W2[lrow + 16];
    const float bb0 = b1[lrow], bb1 = b1[lrow + 16];
    const f32x4 cb0 = {bb0, bb0, bb0, bb0};   // C-in = b1[g] (g = col = lrow)
    const f32x4 cb1 = {bb1, bb1, bb1, bb1};
    const float b2s = b2[0] * (1.0f / 16.0f); // 16 g-lanes contribute per j

    __syncthreads();   // xs visible; no barriers in the main loop

    float S = 0.f, T0 = 0.f, T1 = 0.f, T2 = 0.f;
    float rA[Hc], rB[Hc];

    // 32 coalesced saddr streams: uniform base per h, lane voffset = j+1
    auto L = [&](float (&r)[Hc], int k) {
        const int jj0 = (w * 4 + k) * 64 + lane;
        const int jj  = jj0 < Nc ? jj0 : Nc - 1;   // clamp; masked in epilogue
        const int vo  = jj + 1;
        #pragma unroll
        for (int h = 0; h < Hc; ++h)
            r[h] = qk_b[(size_t)h * PLANE + vo];
    };

    // pack to bf16 (compiler emits v_cvt_pk_bf16_f32) and write wave strip
    auto STAGE = [&](const float (&r)[Hc]) {
        #pragma unroll
        for (int q4 = 0; q4 < 4; ++q4) {
            unsigned pk[4];
            #pragma unroll
            for (int e = 0; e < 4; ++e) {
                __hip_bfloat162 h2 = __float22bfloat162_rn(
                    make_float2(r[q4*8 + 2*e], r[q4*8 + 2*e + 1]));
                pk[e] = *reinterpret_cast<unsigned*>(&h2);
            }
            *reinterpret_cast<uint4*>(&qs[w][lane][q4*8]) =
                make_uint4(pk[0], pk[1], pk[2], pk[3]);
        }
    };

    auto COMP = [&](int k) {
        const int sw = w * 4 + k;
        #pragma unroll
        for (int m = 0; m < 4; ++m) {
            bf16x8 A = *reinterpret_cast<const bf16x8*>(&qs[w][m*16 + lrow][lk*8]);
            f32x4 c0 = __builtin_amdgcn_mfma_f32_16x16x32_bf16(A, B0, cb0, 0, 0, 0);
            f32x4 c1 = __builtin_amdgcn_mfma_f32_16x16x32_bf16(A, B1, cb1, 0, 0, 0);
            const int jb = sw * 64 + m * 16 + lk * 4;   // this lane's 4 j's
            const float* xp = &xs[jb][0];
            f32x4 xA = *reinterpret_cast<const f32x4*>(xp);
            f32x4 xB = *reinterpret_cast<const f32x4*>(xp + 4);
            f32x4 xC = *reinterpret_cast<const f32x4*>(xp + 8);
            const float xj[4][3] = {{xA.x, xA.y, xA.z}, {xA.w, xB.x, xB.y},
                                    {xB.z, xB.w, xC.x}, {xC.y, xC.z, xC.w}};
            #pragma unroll
            for (int r = 0; r < 4; ++r) {
                // per-lane PARTIAL c (this lane's 2 of 32 g's) — linear, so
                // the block reduction recovers the exact totals (R2 pattern)
                float cp = fmaf(fmaxf(c0[r], 0.f), w2a,
                             fmaf(fmaxf(c1[r], 0.f), w2b, b2s));
                if (sw == 15 && m == 3)
                    cp = (jb + r < Nc) ? cp : 0.f;     // only j=1023 invalid
                S += cp;
                T0 = fmaf(xj[r][0], cp, T0);
                T1 = fmaf(xj[r][1], cp, T1);
                T2 = fmaf(xj[r][2], cp, T2);
            }
        }
    };

    // 2-deep register pipeline: loads-in-flight never reach zero.
    // STAGE(rA) waits only tile-k loads (vmcnt counted); rB / reissued rA
    // stay outstanding through every drain.
    L(rA, 0);
    L(rB, 1);
    STAGE(rA); L(rA, 2);
    COMP(0);
    STAGE(rB); L(rB, 3);
    COMP(1);
    STAGE(rA);
    COMP(2);
    STAGE(rB);
    COMP(3);

    // ---- block reduction ----
    #pragma unroll
    for (int off = 32; off > 0; off >>= 1) {
        S  += __shfl_down(S,  off);
        T0 += __shfl_down(T0, off);
        T1 += __shfl_down(T1, off);
        T2 += __shfl_down(T2, off);
    }
    if (lane == 0) { red[w][0] = S; red[w][1] = T0; red[w][2] = T1; red[w][3] = T2; }
    __syncthreads();

    if (t == 0) {
        float s = 0.f, u0 = 0.f, u1 = 0.f, u2 = 0.f;
        #pragma unroll
        for (int q = 0; q < 4; ++q) {
            s += red[q][0]; u0 += red[q][1]; u1 += red[q][2]; u2 += red[q][3];
        }
        const float xi0 = xs[i][0], xi1 = xs[i][1], xi2 = xs[i][2];
        out[(b*Nc + i)*3 + 0] = fmaf(xi0, s, xi0) - u0;
        out[(b*Nc + i)*3 + 1] = fmaf(xi1, s, xi1) - u1;
        out[(b*Nc + i)*3 + 2] = fmaf(xi2, s, xi2) - u2;
    }
}

extern "C" void kernel_launch(void* const* d_in, const int* in_sizes, int n_in,
                              void* d_out, int out_size, void* d_ws, size_t ws_size,
                              hipStream_t stream) {
    const float* x  = (const float*)d_in[0];
    const float* qk = (const float*)d_in[1];
    const float* W1 = (const float*)d_in[2];
    const float* b1 = (const float*)d_in[3];
    const float* W2 = (const float*)d_in[4];
    const float* b2 = (const float*)d_in[5];
    float* out = (float*)d_out;

    se3_head_kernel<<<dim3(Bc * Nc), dim3(BLOCK), 0, stream>>>(
        x, qk, W1, b1, W2, b2, out);
}

// Round 7
// 54.110 us; speedup vs baseline: 1.5754x; 1.3959x over previous
//
#include <hip/hip_runtime.h>
#include <hip/hip_bf16.h>

#define Bc 2
#define Hc 32
#define N1c 1024
#define Nc 1023
#define BLOCK 256
#define PLANE (N1c * N1c)
#define LDSW 40   // 80 B LDS rows: 16B-aligned, 2-way-max banks (R2-proven)

typedef __attribute__((ext_vector_type(8))) short bf16x8;
typedef __attribute__((ext_vector_type(4))) float f32x4;

__device__ __forceinline__ unsigned short f2bf(float a) {
    unsigned ua = __float_as_uint(a);
    ua = (ua + 0x7fffu + ((ua >> 16) & 1u)) >> 16;
    return (unsigned short)ua;
}

__global__ __launch_bounds__(BLOCK, 3) void se3_head_kernel(
    const float* __restrict__ x,    // [B,N,3]
    const float* __restrict__ qk,   // [B,H,N1,N1]
    const float* __restrict__ W1,   // [H,H]
    const float* __restrict__ b1,   // [H]
    const float* __restrict__ W2,   // [1,H]
    const float* __restrict__ b2,   // [1]
    float* __restrict__ out)        // [B,N,3]
{
    __shared__ unsigned short qs[2][256][LDSW];  // double-buffered j'-tile [j''][h]
    __shared__ float xs[N1c][3];                 // xs[j'] = x[j'-1]; xs[0]=0
    __shared__ float red[4][4];

    const int bi   = blockIdx.x;
    const int b    = bi / Nc;
    const int i    = bi % Nc;
    const int t    = threadIdx.x;
    const int w    = t >> 6;
    const int lane = t & 63;
    const int jl   = lane & 15;   // A-row (j'' within 16) / C-col (g)
    const int lk   = lane >> 4;   // k-chunk / C-row-quad

    // row base: qk[b, h, i+1, :]; tiles cover raw columns j' = 0..1023 (aligned)
    const float* qk_row = qk + (size_t)b * Hc * PLANE + (size_t)(i + 1) * N1c;
    const float* xb     = x + (size_t)b * Nc * 3;

    // ---- stage x once: xs[j'] = x[j'-1], xs[0] = 0 ----
    for (int rr = t; rr < N1c; rr += BLOCK) {
        float v0 = 0.f, v1 = 0.f, v2 = 0.f;
        if (rr >= 1) { v0 = xb[(rr-1)*3]; v1 = xb[(rr-1)*3+1]; v2 = xb[(rr-1)*3+2]; }
        xs[rr][0] = v0; xs[rr][1] = v1; xs[rr][2] = v2;
    }

    // ---- per-lane constants (R2/R6-verified geometry + numerics) ----
    bf16x8 B0, B1;   // B[k=h=lk*8+e][col=g=jl] = W1[g][h], cols g and g+16
    #pragma unroll
    for (int e = 0; e < 8; ++e) {
        ((unsigned short*)&B0)[e] = f2bf(W1[jl * Hc + lk*8 + e]);
        ((unsigned short*)&B1)[e] = f2bf(W1[(jl + 16) * Hc + lk*8 + e]);
    }
    const float w2a = W2[jl], w2b = W2[jl + 16];
    const float bb0 = b1[jl], bb1 = b1[jl + 16];
    const f32x4 cb0 = {bb0, bb0, bb0, bb0};   // C-in = b1[g], g = col = jl
    const f32x4 cb1 = {bb1, bb1, bb1, bb1};
    const float b2s = b2[0] * (1.0f / 16.0f); // 16 g-lanes contribute per j

    float S = 0.f, T0 = 0.f, T1 = 0.f, T2 = 0.f;
    float rA[Hc], rB[Hc];   // two DISTINCT reg sets: no renaming, ping-pong

    // 32 coalesced streams: lane = j'' (thread t), uniform per-h base
    auto L = [&](float (&r)[Hc], int k) {
        const float* p = qk_row + k * 256 + t;
        #pragma unroll
        for (int h = 0; h < Hc; ++h)
            r[h] = p[(size_t)h * PLANE];
    };

    // pack 32 floats -> 16 bf16x2 dwords (v_cvt_pk_bf16_f32), 4x ds_write_b128
    auto STAGE = [&](const float (&r)[Hc], int buf) {
        #pragma unroll
        for (int q4 = 0; q4 < 4; ++q4) {
            unsigned pk[4];
            #pragma unroll
            for (int e = 0; e < 4; ++e) {
                __hip_bfloat162 h2 = __float22bfloat162_rn(
                    make_float2(r[q4*8 + 2*e], r[q4*8 + 2*e + 1]));
                pk[e] = *reinterpret_cast<unsigned*>(&h2);
            }
            *reinterpret_cast<uint4*>(&qs[buf][t][q4*8]) =
                make_uint4(pk[0], pk[1], pk[2], pk[3]);
        }
    };

    auto COMP = [&](int k, int buf) {
        #pragma unroll
        for (int m = 0; m < 4; ++m) {
            const int row = w * 64 + m * 16;                 // wave-owned rows
            bf16x8 A = *reinterpret_cast<const bf16x8*>(&qs[buf][row + jl][lk*8]);
            f32x4 c0 = __builtin_amdgcn_mfma_f32_16x16x32_bf16(A, B0, cb0, 0, 0, 0);
            f32x4 c1 = __builtin_amdgcn_mfma_f32_16x16x32_bf16(A, B1, cb1, 0, 0, 0);
            const int jb = k * 256 + row + lk * 4;           // this lane's 4 j'
            const float* xp = &xs[jb][0];                    // 16B-aligned (jb%4==0)
            f32x4 xA = *reinterpret_cast<const f32x4*>(xp);
            f32x4 xB = *reinterpret_cast<const f32x4*>(xp + 4);
            f32x4 xC = *reinterpret_cast<const f32x4*>(xp + 8);
            const float xj[4][3] = {{xA.x, xA.y, xA.z}, {xA.w, xB.x, xB.y},
                                    {xB.z, xB.w, xC.x}, {xC.y, xC.z, xC.w}};
            #pragma unroll
            for (int r = 0; r < 4; ++r) {
                float cp = fmaf(fmaxf(c0[r], 0.f), w2a,
                             fmaf(fmaxf(c1[r], 0.f), w2b, b2s));
                if (k == 0 && m == 0)                        // only j'==0 invalid
                    cp = (jb + r == 0) ? 0.f : cp;
                S += cp;
                T0 = fmaf(xj[r][0], cp, T0);
                T1 = fmaf(xj[r][1], cp, T1);
                T2 = fmaf(xj[r][2], cp, T2);
            }
        }
    };

    // ---- pipeline: loads-in-flight never reach zero; 1 barrier per tile ----
    L(rA, 0); L(rB, 1);
    STAGE(rA, 0);
    __syncthreads();            // also publishes xs

    L(rA, 2);                   // tile-2 loads fly during COMP(0)+STAGE(1)
    COMP(0, 0);
    STAGE(rB, 1);
    __syncthreads();

    L(rB, 3);                   // tile-3 loads fly during COMP(1)+STAGE(2)
    COMP(1, 1);
    STAGE(rA, 0);
    __syncthreads();

    COMP(2, 0);
    STAGE(rB, 1);
    __syncthreads();

    COMP(3, 1);

    // ---- block reduction ----
    #pragma unroll
    for (int off = 32; off > 0; off >>= 1) {
        S  += __shfl_down(S,  off);
        T0 += __shfl_down(T0, off);
        T1 += __shfl_down(T1, off);
        T2 += __shfl_down(T2, off);
    }
    if (lane == 0) { red[w][0] = S; red[w][1] = T0; red[w][2] = T1; red[w][3] = T2; }
    __syncthreads();

    if (t == 0) {
        float s = 0.f, u0 = 0.f, u1 = 0.f, u2 = 0.f;
        #pragma unroll
        for (int q = 0; q < 4; ++q) {
            s += red[q][0]; u0 += red[q][1]; u1 += red[q][2]; u2 += red[q][3];
        }
        const float xi0 = xs[i+1][0], xi1 = xs[i+1][1], xi2 = xs[i+1][2];
        out[(b*Nc + i)*3 + 0] = fmaf(xi0, s, xi0) - u0;
        out[(b*Nc + i)*3 + 1] = fmaf(xi1, s, xi1) - u1;
        out[(b*Nc + i)*3 + 2] = fmaf(xi2, s, xi2) - u2;
    }
}

extern "C" void kernel_launch(void* const* d_in, const int* in_sizes, int n_in,
                              void* d_out, int out_size, void* d_ws, size_t ws_size,
                              hipStream_t stream) {
    const float* x  = (const float*)d_in[0];
    const float* qk = (const float*)d_in[1];
    const float* W1 = (const float*)d_in[2];
    const float* b1 = (const float*)d_in[3];
    const float* W2 = (const float*)d_in[4];
    const float* b2 = (const float*)d_in[5];
    float* out = (float*)d_out;

    se3_head_kernel<<<dim3(Bc * Nc), dim3(BLOCK), 0, stream>>>(
        x, qk, W1, b1, W2, b2, out);
}